// Round 9
// baseline (1225.467 us; speedup 1.0000x reference)
//
#include <hip/hip_runtime.h>
#include <hip/hip_bf16.h>

typedef __attribute__((ext_vector_type(8))) short short8;
typedef __attribute__((ext_vector_type(4))) float f32x4;

#define T_TOK 8192
#define DMODEL 1024
#define HFFN 4096
#define NEXP 4

__device__ __forceinline__ ushort f2b(float f) {
    __hip_bfloat16 h = __float2bfloat16(f);
    return __builtin_bit_cast(ushort, h);
}

__device__ __forceinline__ void glds16(const void* g, void* l) {
    __builtin_amdgcn_global_load_lds(
        (__attribute__((address_space(1))) void*)g,
        (__attribute__((address_space(3))) void*)l, 16, 0, 0);
}

// ---------------- gate + x->bf16 fusion + ballot-aggregated routing ----------
__global__ __launch_bounds__(256) void gate_kernel(
        const float* __restrict__ x, const float* __restrict__ gw,
        ushort* __restrict__ Xb, float* __restrict__ gdense,
        int* __restrict__ counts, int* __restrict__ lists) {
    const int lane = threadIdx.x & 63;
    const int w = threadIdx.x >> 6;
    __shared__ int top2s[32];

    float4 wv[4][4];
#pragma unroll
    for (int p = 0; p < 4; p++)
#pragma unroll
        for (int e = 0; e < 4; e++)
            wv[p][e] = *(const float4*)&gw[e * DMODEL + p * 256 + lane * 4];

    const int t0 = blockIdx.x * 32 + w * 8;
#pragma unroll
    for (int i = 0; i < 8; i++) {
        const int t = t0 + i;
        const float* xr = x + (size_t)t * DMODEL;
        ushort* xbr = Xb + (size_t)t * DMODEL;
        float acc[4] = {0.f, 0.f, 0.f, 0.f};
#pragma unroll
        for (int p = 0; p < 4; p++) {
            float4 xv = *(const float4*)&xr[p * 256 + lane * 4];
            ushort4 o;
            o.x = f2b(xv.x); o.y = f2b(xv.y); o.z = f2b(xv.z); o.w = f2b(xv.w);
            *(ushort4*)&xbr[p * 256 + lane * 4] = o;
#pragma unroll
            for (int e = 0; e < 4; e++)
                acc[e] += xv.x * wv[p][e].x + xv.y * wv[p][e].y +
                          xv.z * wv[p][e].z + xv.w * wv[p][e].w;
        }
#pragma unroll
        for (int e = 0; e < 4; e++)
#pragma unroll
            for (int s = 1; s < 64; s <<= 1) acc[e] += __shfl_xor(acc[e], s);
        if (lane == 0) {
            int i0 = 0; float v0 = acc[0];
#pragma unroll
            for (int e = 1; e < 4; e++) if (acc[e] > v0) { v0 = acc[e]; i0 = e; }
            int i1 = -1; float v1 = -INFINITY;
#pragma unroll
            for (int e = 0; e < 4; e++) if (e != i0 && acc[e] > v1) { v1 = acc[e]; i1 = e; }
            float e1 = expf(v1 - v0);
            float w0 = 1.0f / (1.0f + e1);
            float w1 = e1 / (1.0f + e1);
            float o[4] = {0.f, 0.f, 0.f, 0.f};
            o[i0] = w0; o[i1] = w1;
            *(float4*)&gdense[t * 4] = make_float4(o[0], o[1], o[2], o[3]);
            top2s[w * 8 + i] = i0 | (i1 << 4);
        }
    }
    __syncthreads();
    if (w == 0) {
        int i0 = -1, i1 = -1;
        if (lane < 32) {
            const int pk = top2s[lane];
            i0 = pk & 15; i1 = pk >> 4;
        }
        const unsigned long long below = (1ull << lane) - 1;
        const int t = blockIdx.x * 32 + lane;
#pragma unroll
        for (int e = 0; e < 4; e++) {
            unsigned long long m0 = __ballot(i0 == e);
            unsigned long long m1 = __ballot(i1 == e);
            const int c0 = __popcll(m0);
            const int c1 = __popcll(m1);
            int base = 0;
            if (lane == 0 && (c0 + c1) > 0) base = atomicAdd(&counts[e], c0 + c1);
            base = __shfl(base, 0);
            if (i0 == e) lists[e * T_TOK + base + __popcll(m0 & below)] = t;
            if (i1 == e) lists[e * T_TOK + base + c0 + __popcll(m1 & below)] = t;
        }
    }
}

// ---------------- fp32 [Kd][Nd] -> bf16 [Nd][Kd] (batched over z) -------------
__global__ void transpose_cvt(const float* __restrict__ in, ushort* __restrict__ out,
                              int Kd, int Nd) {
    __shared__ float tile[32][33];
    const size_t mat = (size_t)Kd * Nd;
    const float* ip = in + (size_t)blockIdx.z * mat;
    ushort* op = out + (size_t)blockIdx.z * mat;
    const int n0 = blockIdx.x * 32, k0 = blockIdx.y * 32;
    const int tx = threadIdx.x, ty = threadIdx.y;  // (32, 8)
#pragma unroll
    for (int j = 0; j < 4; j++)
        tile[ty + j * 8][tx] = ip[(size_t)(k0 + ty + j * 8) * Nd + n0 + tx];
    __syncthreads();
#pragma unroll
    for (int j = 0; j < 4; j++)
        op[(size_t)(n0 + ty + j * 8) * Kd + k0 + tx] = f2b(tile[tx][ty + j * 8]);
}

// -------- FFN GEMM (2-phase dbuf, m97 core), batched-over-experts when ROUTED --
// PHASE1: A rows from Xb (gathered if ROUTED), B = W1^T; h[(pfx+r)][c] = gelu(v+b1)
// PHASE2: A = h rows pfx+r (contiguous), B = W2^T;
//         ROUTED: unsafeAtomicAdd(out[tok][c], g*(v+b2));  else out[r][c] = v+sb2
template <int PHASE, bool ROUTED>
__launch_bounds__(256)
__global__ void ffn_gemm(const ushort* __restrict__ Abase,
                         ushort* __restrict__ hOut,
                         float* __restrict__ yOut,
                         const ushort* __restrict__ Wbase,
                         const float* __restrict__ biasBase,
                         const float* __restrict__ gdense,
                         const int* __restrict__ lists,
                         const int* __restrict__ counts) {
    constexpr int Nn = (PHASE == 1) ? HFFN : DMODEL;
    constexpr int Kd = (PHASE == 1) ? DMODEL : HFFN;
    constexpr int BN = (PHASE == 1) ? 128 : 64;
    constexpr int NC = Nn / BN;
    constexpr int SEC = 64 * NC;          // capacity row-tiles(64) x col-tiles
    constexpr int BK = 32;
    constexpr int MW = (BN == 128) ? 4 : 2;
    constexpr int NW = 4;

    __shared__ ushort As[2][128 * BK];
    __shared__ ushort Bs[2][BN * BK];

    int sec, id;
    if (ROUTED) { sec = blockIdx.x / SEC; id = blockIdx.x % SEC; }
    else        { sec = 0; id = blockIdx.x; }
    // bijective XCD chunking (SEC % 8 == 0): each XCD owns contiguous row-tiles
    id = (id & 7) * (SEC >> 3) + (id >> 3);

    const int cnt = ROUTED ? counts[sec] : T_TOK;
    const int row0 = (id / NC) * 128;
    if (row0 >= cnt) return;
    const int col0 = (id % NC) * BN;
    int pfx = 0;
    if (ROUTED) for (int i = 0; i < sec; i++) pfx += counts[i];
    const int* list_s = ROUTED ? (lists + sec * T_TOK) : nullptr;
    const ushort* Bt = Wbase + (ROUTED ? (size_t)sec * Kd * Nn : 0);
    const float* bias = biasBase + (ROUTED ? sec * Nn : 0);

    const int tid = threadIdx.x;
    const int lane = tid & 63, wid = tid >> 6;
    const int rowbase = (BN == 128) ? (wid >> 1) * 64 : wid * 32;
    const int colbase = (BN == 128) ? (wid & 1) * 64 : 0;

    const int s_r = tid >> 2;
    const int s_k = (tid & 3) * 8;

    int l0 = row0 + s_r;       if (l0 >= cnt) l0 = cnt - 1;
    int l1 = row0 + 64 + s_r;  if (l1 >= cnt) l1 = cnt - 1;
    size_t ar0, ar1;
    if (PHASE == 1) {
        ar0 = ROUTED ? (size_t)list_s[l0] : (size_t)l0;
        ar1 = ROUTED ? (size_t)list_s[l1] : (size_t)l1;
    } else {
        ar0 = (size_t)(pfx + l0);
        ar1 = (size_t)(pfx + l1);
    }
    const ushort* Ap0 = Abase + ar0 * Kd + s_k;
    const ushort* Ap1 = Abase + ar1 * Kd + s_k;
    const ushort* Bp0 = Bt + (size_t)(col0 + s_r) * Kd + s_k;
    const ushort* Bp1 = Bt + (size_t)(col0 + 64 + s_r) * Kd + s_k;  // BN==128 only

    auto stage = [&](int buf, int k0) {
        glds16(Ap0 + k0, &As[buf][wid * 512]);
        glds16(Ap1 + k0, &As[buf][2048 + wid * 512]);
        glds16(Bp0 + k0, &Bs[buf][wid * 512]);
        if (BN == 128) glds16(Bp1 + k0, &Bs[buf][2048 + wid * 512]);
    };

    f32x4 acc[MW][NW] = {};
    const int lr = lane & 15, lk = (lane >> 4) * 8;

    auto compute = [&](int buf) {
        short8 af[MW], bf[NW];
#pragma unroll
        for (int m = 0; m < MW; m++)
            af[m] = *(const short8*)&As[buf][(rowbase + m * 16 + lr) * BK + lk];
#pragma unroll
        for (int n = 0; n < NW; n++)
            bf[n] = *(const short8*)&Bs[buf][(colbase + n * 16 + lr) * BK + lk];
#pragma unroll
        for (int m = 0; m < MW; m++)
#pragma unroll
            for (int n = 0; n < NW; n++)
                acc[m][n] = __builtin_amdgcn_mfma_f32_16x16x32_bf16(af[m], bf[n], acc[m][n], 0, 0, 0);
    };

    stage(0, 0);
    __syncthreads();
    int cur = 0;
    constexpr int nk = Kd / BK;
    for (int t = 0; t < nk - 1; ++t) {
        stage(cur ^ 1, (t + 1) * BK);
        compute(cur);
        __syncthreads();
        cur ^= 1;
    }
    compute(cur);

    // epilogue: C/D layout col = lane&15, row = (lane>>4)*4 + j  [verified]
    const int lq = lane >> 4;
#pragma unroll
    for (int m = 0; m < MW; m++) {
        const int r_base = row0 + rowbase + m * 16 + lq * 4;
#pragma unroll
        for (int n = 0; n < NW; n++) {
            const int c = col0 + colbase + n * 16 + lr;
            const float b = bias[c];
#pragma unroll
            for (int j = 0; j < 4; j++) {
                const int r = r_base + j;
                if (r >= cnt) continue;
                float v = acc[m][n][j] + b;
                if (PHASE == 1) {
                    // gelu(v) = v*sigmoid(1.5957691*t2), t2 = v + 0.044715 v^3
                    // sigmoid(y) = 1 - 1/(1+e^y); e^y = exp2(1.5957691*log2e*t2),
                    // constant = 1.5957691216 * 1.4426950409 = 2.3022082  [R8 bug: was 2x]
                    float v2 = v * v;
                    float t2 = __builtin_fmaf(0.044715f, v2 * v, v);
                    float e = __builtin_amdgcn_exp2f(2.3022082f * t2);
                    float rr = __builtin_amdgcn_rcpf(e + 1.0f);
                    hOut[(size_t)(pfx + r) * HFFN + c] = f2b(v - v * rr);
                } else if (ROUTED) {
                    const int tok = list_s[r];
                    const float g = gdense[tok * 4 + sec];
                    unsafeAtomicAdd(&yOut[(size_t)tok * DMODEL + c], g * v);
                } else {
                    yOut[(size_t)r * DMODEL + c] = v;
                }
            }
        }
    }
}

extern "C" void kernel_launch(void* const* d_in, const int* in_sizes, int n_in,
                              void* d_out, int out_size, void* d_ws, size_t ws_size,
                              hipStream_t stream) {
    const float* x      = (const float*)d_in[0];
    const float* gate_w = (const float*)d_in[1];
    const float* W1     = (const float*)d_in[2];
    const float* b1     = (const float*)d_in[3];
    const float* W2     = (const float*)d_in[4];
    const float* b2     = (const float*)d_in[5];
    const float* sW1    = (const float*)d_in[6];
    const float* sb1    = (const float*)d_in[7];
    const float* sW2    = (const float*)d_in[8];
    const float* sb2    = (const float*)d_in[9];
    float* out = (float*)d_out;

    // ---- lifetime-phased workspace layout, peak ~176.3 MB (< proven-safe 192.6) --
    char* ws = (char*)d_ws;
    ushort* hArea  = (ushort*)(ws);                          // 128 MB: hS then hR
    ushort* Xb     = (ushort*)(ws + (size_t)128 * 1024 * 1024);      // 16 MB
    ushort* Wt     = (ushort*)(ws + (size_t)144 * 1024 * 1024);      // 32 MB shared region
    ushort* Wt8    = Wt + (size_t)4 * 1024 * 1024;                   // +8 MB (ushort elems)
    float*  gdense = (float*)(ws + (size_t)176 * 1024 * 1024);       // 128 KB
    int*    counts = (int*)(ws + (size_t)176 * 1024 * 1024 + 131072);
    int*    lists  = (int*)(ws + (size_t)176 * 1024 * 1024 + 131072 + 256);

    hipMemsetAsync(counts, 0, NEXP * sizeof(int), stream);

    // gate + fused x->bf16
    gate_kernel<<<T_TOK / 32, 256, 0, stream>>>(x, gate_w, Xb, gdense, counts, lists);

    // ---- shared expert first (h uses hArea[0:64MB)) ----
    transpose_cvt<<<dim3(HFFN / 32, DMODEL / 32, 1), dim3(32, 8), 0, stream>>>(sW1, Wt, DMODEL, HFFN);
    transpose_cvt<<<dim3(DMODEL / 32, HFFN / 32, 1), dim3(32, 8), 0, stream>>>(sW2, Wt8, HFFN, DMODEL);
    ffn_gemm<1, false><<<64 * 32, 256, 0, stream>>>(Xb, hArea, nullptr, Wt, sb1,
                                                    nullptr, nullptr, nullptr);
    ffn_gemm<2, false><<<64 * 16, 256, 0, stream>>>(hArea, nullptr, out, Wt8, sb2,
                                                    nullptr, nullptr, nullptr);

    // ---- routed experts, batched single dispatches ----
    transpose_cvt<<<dim3(HFFN / 32, DMODEL / 32, NEXP), dim3(32, 8), 0, stream>>>(W1, Wt, DMODEL, HFFN);
    ffn_gemm<1, true><<<NEXP * 64 * 32, 256, 0, stream>>>(Xb, hArea, nullptr, Wt, b1,
                                                          nullptr, lists, counts);
    transpose_cvt<<<dim3(DMODEL / 32, HFFN / 32, NEXP), dim3(32, 8), 0, stream>>>(W2, Wt, HFFN, DMODEL);
    ffn_gemm<2, true><<<NEXP * 64 * 16, 256, 0, stream>>>(hArea, nullptr, out, Wt, b2,
                                                          gdense, lists, counts);
}

// Round 10
// 1177.585 us; speedup vs baseline: 1.0407x; 1.0407x over previous
//
#include <hip/hip_runtime.h>
#include <hip/hip_bf16.h>

typedef __attribute__((ext_vector_type(8))) short short8;
typedef __attribute__((ext_vector_type(4))) float f32x4;

#define T_TOK 8192
#define DMODEL 1024
#define HFFN 4096
#define NEXP 4

__device__ __forceinline__ ushort f2b(float f) {
    __hip_bfloat16 h = __float2bfloat16(f);
    return __builtin_bit_cast(ushort, h);
}
__device__ __forceinline__ float b2f(unsigned u) {  // low 16 bits = bf16
    return __builtin_bit_cast(float, u << 16);
}

__device__ __forceinline__ void glds16(const void* g, void* l) {
    __builtin_amdgcn_global_load_lds(
        (__attribute__((address_space(1))) void*)g,
        (__attribute__((address_space(3))) void*)l, 16, 0, 0);
}

// ---------------- gate + x->bf16 fusion + ballot-aggregated routing ----------
// list entry = tok | (slot << 16); slot 0 = top-1 pick, slot 1 = top-2 pick.
__global__ __launch_bounds__(256) void gate_kernel(
        const float* __restrict__ x, const float* __restrict__ gw,
        ushort* __restrict__ Xb, float* __restrict__ gdense,
        int* __restrict__ counts, int* __restrict__ lists) {
    const int lane = threadIdx.x & 63;
    const int w = threadIdx.x >> 6;
    __shared__ int top2s[32];

    float4 wv[4][4];
#pragma unroll
    for (int p = 0; p < 4; p++)
#pragma unroll
        for (int e = 0; e < 4; e++)
            wv[p][e] = *(const float4*)&gw[e * DMODEL + p * 256 + lane * 4];

    const int t0 = blockIdx.x * 32 + w * 8;
#pragma unroll
    for (int i = 0; i < 8; i++) {
        const int t = t0 + i;
        const float* xr = x + (size_t)t * DMODEL;
        ushort* xbr = Xb + (size_t)t * DMODEL;
        float acc[4] = {0.f, 0.f, 0.f, 0.f};
#pragma unroll
        for (int p = 0; p < 4; p++) {
            float4 xv = *(const float4*)&xr[p * 256 + lane * 4];
            ushort4 o;
            o.x = f2b(xv.x); o.y = f2b(xv.y); o.z = f2b(xv.z); o.w = f2b(xv.w);
            *(ushort4*)&xbr[p * 256 + lane * 4] = o;
#pragma unroll
            for (int e = 0; e < 4; e++)
                acc[e] += xv.x * wv[p][e].x + xv.y * wv[p][e].y +
                          xv.z * wv[p][e].z + xv.w * wv[p][e].w;
        }
#pragma unroll
        for (int e = 0; e < 4; e++)
#pragma unroll
            for (int s = 1; s < 64; s <<= 1) acc[e] += __shfl_xor(acc[e], s);
        if (lane == 0) {
            int i0 = 0; float v0 = acc[0];
#pragma unroll
            for (int e = 1; e < 4; e++) if (acc[e] > v0) { v0 = acc[e]; i0 = e; }
            int i1 = -1; float v1 = -INFINITY;
#pragma unroll
            for (int e = 0; e < 4; e++) if (e != i0 && acc[e] > v1) { v1 = acc[e]; i1 = e; }
            float e1 = expf(v1 - v0);
            float w0 = 1.0f / (1.0f + e1);
            float w1 = e1 / (1.0f + e1);
            float o[4] = {0.f, 0.f, 0.f, 0.f};
            o[i0] = w0; o[i1] = w1;
            *(float4*)&gdense[t * 4] = make_float4(o[0], o[1], o[2], o[3]);
            top2s[w * 8 + i] = i0 | (i1 << 4);
        }
    }
    __syncthreads();
    if (w == 0) {
        int i0 = -1, i1 = -1;
        if (lane < 32) {
            const int pk = top2s[lane];
            i0 = pk & 15; i1 = pk >> 4;
        }
        const unsigned long long below = (1ull << lane) - 1;
        const int t = blockIdx.x * 32 + lane;
#pragma unroll
        for (int e = 0; e < 4; e++) {
            unsigned long long m0 = __ballot(i0 == e);
            unsigned long long m1 = __ballot(i1 == e);
            const int c0 = __popcll(m0);
            const int c1 = __popcll(m1);
            int base = 0;
            if (lane == 0 && (c0 + c1) > 0) base = atomicAdd(&counts[e], c0 + c1);
            base = __shfl(base, 0);
            if (i0 == e) lists[e * T_TOK + base + __popcll(m0 & below)] = t;                 // slot 0
            if (i1 == e) lists[e * T_TOK + base + c0 + __popcll(m1 & below)] = t | 0x10000;  // slot 1
        }
    }
}

// ---------------- fp32 [Kd][Nd] -> bf16 [Nd][Kd] (batched over z) -------------
__global__ void transpose_cvt(const float* __restrict__ in, ushort* __restrict__ out,
                              int Kd, int Nd) {
    __shared__ float tile[32][33];
    const size_t mat = (size_t)Kd * Nd;
    const float* ip = in + (size_t)blockIdx.z * mat;
    ushort* op = out + (size_t)blockIdx.z * mat;
    const int n0 = blockIdx.x * 32, k0 = blockIdx.y * 32;
    const int tx = threadIdx.x, ty = threadIdx.y;  // (32, 8)
#pragma unroll
    for (int j = 0; j < 4; j++)
        tile[ty + j * 8][tx] = ip[(size_t)(k0 + ty + j * 8) * Nd + n0 + tx];
    __syncthreads();
#pragma unroll
    for (int j = 0; j < 4; j++)
        op[(size_t)(n0 + ty + j * 8) * Kd + k0 + tx] = f2b(tile[tx][ty + j * 8]);
}

// -------- FFN GEMM (2-phase dbuf, m97 core), batched-over-experts when ROUTED --
// PHASE1: A rows from Xb (gathered if ROUTED), B = W1^T; h[(pfx+r)][c] = gelu(v+b1)
// PHASE2 ROUTED: packed ushort store: uOut[2*(tok*D + c) + slot] = bf16(g*(v+b2))
// PHASE2 !ROUTED: uOut[r*D + c] = bf16(v + sb2)          (shared partial, bf16)
template <int PHASE, bool ROUTED>
__launch_bounds__(256)
__global__ void ffn_gemm(const ushort* __restrict__ Abase,
                         ushort* __restrict__ hOut,
                         ushort* __restrict__ uOut,
                         const ushort* __restrict__ Wbase,
                         const float* __restrict__ biasBase,
                         const float* __restrict__ gdense,
                         const int* __restrict__ lists,
                         const int* __restrict__ counts) {
    constexpr int Nn = (PHASE == 1) ? HFFN : DMODEL;
    constexpr int Kd = (PHASE == 1) ? DMODEL : HFFN;
    constexpr int BN = (PHASE == 1) ? 128 : 64;
    constexpr int NC = Nn / BN;
    constexpr int SEC = 64 * NC;          // capacity row-tiles(64) x col-tiles
    constexpr int BK = 32;
    constexpr int MW = (BN == 128) ? 4 : 2;
    constexpr int NW = 4;

    __shared__ ushort As[2][128 * BK];
    __shared__ ushort Bs[2][BN * BK];

    int sec, id;
    if (ROUTED) { sec = blockIdx.x / SEC; id = blockIdx.x % SEC; }
    else        { sec = 0; id = blockIdx.x; }
    // bijective XCD chunking (SEC % 8 == 0): each XCD owns contiguous row-tiles
    id = (id & 7) * (SEC >> 3) + (id >> 3);

    const int cnt = ROUTED ? counts[sec] : T_TOK;
    const int row0 = (id / NC) * 128;
    if (row0 >= cnt) return;
    const int col0 = (id % NC) * BN;
    int pfx = 0;
    if (ROUTED) for (int i = 0; i < sec; i++) pfx += counts[i];
    const int* list_s = ROUTED ? (lists + sec * T_TOK) : nullptr;
    const ushort* Bt = Wbase + (ROUTED ? (size_t)sec * Kd * Nn : 0);
    const float* bias = biasBase + (ROUTED ? sec * Nn : 0);

    const int tid = threadIdx.x;
    const int lane = tid & 63, wid = tid >> 6;
    const int rowbase = (BN == 128) ? (wid >> 1) * 64 : wid * 32;
    const int colbase = (BN == 128) ? (wid & 1) * 64 : 0;

    const int s_r = tid >> 2;
    const int s_k = (tid & 3) * 8;

    int l0 = row0 + s_r;       if (l0 >= cnt) l0 = cnt - 1;
    int l1 = row0 + 64 + s_r;  if (l1 >= cnt) l1 = cnt - 1;
    size_t ar0, ar1;
    if (PHASE == 1) {
        ar0 = ROUTED ? (size_t)(list_s[l0] & 0xFFFF) : (size_t)l0;
        ar1 = ROUTED ? (size_t)(list_s[l1] & 0xFFFF) : (size_t)l1;
    } else {
        ar0 = (size_t)(pfx + l0);
        ar1 = (size_t)(pfx + l1);
    }
    const ushort* Ap0 = Abase + ar0 * Kd + s_k;
    const ushort* Ap1 = Abase + ar1 * Kd + s_k;
    const ushort* Bp0 = Bt + (size_t)(col0 + s_r) * Kd + s_k;
    const ushort* Bp1 = Bt + (size_t)(col0 + 64 + s_r) * Kd + s_k;  // BN==128 only

    auto stage = [&](int buf, int k0) {
        glds16(Ap0 + k0, &As[buf][wid * 512]);
        glds16(Ap1 + k0, &As[buf][2048 + wid * 512]);
        glds16(Bp0 + k0, &Bs[buf][wid * 512]);
        if (BN == 128) glds16(Bp1 + k0, &Bs[buf][2048 + wid * 512]);
    };

    f32x4 acc[MW][NW] = {};
    const int lr = lane & 15, lk = (lane >> 4) * 8;

    auto compute = [&](int buf) {
        short8 af[MW], bf[NW];
#pragma unroll
        for (int m = 0; m < MW; m++)
            af[m] = *(const short8*)&As[buf][(rowbase + m * 16 + lr) * BK + lk];
#pragma unroll
        for (int n = 0; n < NW; n++)
            bf[n] = *(const short8*)&Bs[buf][(colbase + n * 16 + lr) * BK + lk];
#pragma unroll
        for (int m = 0; m < MW; m++)
#pragma unroll
            for (int n = 0; n < NW; n++)
                acc[m][n] = __builtin_amdgcn_mfma_f32_16x16x32_bf16(af[m], bf[n], acc[m][n], 0, 0, 0);
    };

    stage(0, 0);
    __syncthreads();
    int cur = 0;
    constexpr int nk = Kd / BK;
    for (int t = 0; t < nk - 1; ++t) {
        stage(cur ^ 1, (t + 1) * BK);
        compute(cur);
        __syncthreads();
        cur ^= 1;
    }
    compute(cur);

    // epilogue: C/D layout col = lane&15, row = (lane>>4)*4 + j  [verified]
    const int lq = lane >> 4;
#pragma unroll
    for (int m = 0; m < MW; m++) {
        const int r_base = row0 + rowbase + m * 16 + lq * 4;
#pragma unroll
        for (int n = 0; n < NW; n++) {
            const int c = col0 + colbase + n * 16 + lr;
            const float b = bias[c];
#pragma unroll
            for (int j = 0; j < 4; j++) {
                const int r = r_base + j;
                if (r >= cnt) continue;
                float v = acc[m][n][j] + b;
                if (PHASE == 1) {
                    // gelu(v) = v*sigmoid(1.5957691*t2), t2 = v + 0.044715 v^3
                    // exp2 constant = 1.5957691216 * log2(e) = 2.3022082
                    float v2 = v * v;
                    float t2 = __builtin_fmaf(0.044715f, v2 * v, v);
                    float e = __builtin_amdgcn_exp2f(2.3022082f * t2);
                    float rr = __builtin_amdgcn_rcpf(e + 1.0f);
                    hOut[(size_t)(pfx + r) * HFFN + c] = f2b(v - v * rr);
                } else if (ROUTED) {
                    const int entry = list_s[r];
                    const int tok = entry & 0xFFFF;
                    const int slot = entry >> 16;
                    const float g = gdense[tok * 4 + sec];
                    uOut[((size_t)tok * DMODEL + c) * 2 + slot] = f2b(g * v);
                } else {
                    uOut[(size_t)r * DMODEL + c] = f2b(v);
                }
            }
        }
    }
}

// -------- combine: out[t][c] = lo16 + hi16 (routed pair) + shPart -------------
__global__ __launch_bounds__(256) void combine_kernel(
        float* __restrict__ out, const ushort* __restrict__ shPart) {
    const size_t i4 = ((size_t)blockIdx.x * 256 + threadIdx.x) * 4;
    uint4 p = *(const uint4*)&((const unsigned*)out)[i4];
    ushort4 s = *(const ushort4*)&shPart[i4];
    float4 o;
    o.x = b2f(p.x & 0xffff) + b2f(p.x >> 16) + b2f(s.x);
    o.y = b2f(p.y & 0xffff) + b2f(p.y >> 16) + b2f(s.y);
    o.z = b2f(p.z & 0xffff) + b2f(p.z >> 16) + b2f(s.z);
    o.w = b2f(p.w & 0xffff) + b2f(p.w >> 16) + b2f(s.w);
    *(float4*)&out[i4] = o;
}

extern "C" void kernel_launch(void* const* d_in, const int* in_sizes, int n_in,
                              void* d_out, int out_size, void* d_ws, size_t ws_size,
                              hipStream_t stream) {
    const float* x      = (const float*)d_in[0];
    const float* gate_w = (const float*)d_in[1];
    const float* W1     = (const float*)d_in[2];
    const float* b1     = (const float*)d_in[3];
    const float* W2     = (const float*)d_in[4];
    const float* b2     = (const float*)d_in[5];
    const float* sW1    = (const float*)d_in[6];
    const float* sb1    = (const float*)d_in[7];
    const float* sW2    = (const float*)d_in[8];
    const float* sb2    = (const float*)d_in[9];
    float* out = (float*)d_out;

    // ---- lifetime-phased workspace, peak ~192.3 MiB (<= 192.5 proven-safe) ----
    char* ws = (char*)d_ws;
    ushort* hArea  = (ushort*)(ws);                                  // 128 MiB
    ushort* Xb     = (ushort*)(ws + (size_t)128 * 1024 * 1024);      // 16 MiB
    ushort* Wt     = (ushort*)(ws + (size_t)144 * 1024 * 1024);      // 32 MiB
    ushort* Wt8    = Wt + (size_t)4 * 1024 * 1024;                   // +8 MiB region
    ushort* shPart = (ushort*)(ws + (size_t)176 * 1024 * 1024);      // 16 MiB
    float*  gdense = (float*)(ws + (size_t)192 * 1024 * 1024);       // 128 KiB
    int*    counts = (int*)(ws + (size_t)192 * 1024 * 1024 + 131072);
    int*    lists  = (int*)(ws + (size_t)192 * 1024 * 1024 + 131072 + 256);

    hipMemsetAsync(counts, 0, NEXP * sizeof(int), stream);

    // gate + fused x->bf16
    gate_kernel<<<T_TOK / 32, 256, 0, stream>>>(x, gate_w, Xb, gdense, counts, lists);

    // ---- shared expert first (h uses hArea[0:64MiB)) ----
    transpose_cvt<<<dim3(HFFN / 32, DMODEL / 32, 1), dim3(32, 8), 0, stream>>>(sW1, Wt, DMODEL, HFFN);
    transpose_cvt<<<dim3(DMODEL / 32, HFFN / 32, 1), dim3(32, 8), 0, stream>>>(sW2, Wt8, HFFN, DMODEL);
    ffn_gemm<1, false><<<64 * 32, 256, 0, stream>>>(Xb, hArea, nullptr, Wt, sb1,
                                                    nullptr, nullptr, nullptr);
    ffn_gemm<2, false><<<64 * 16, 256, 0, stream>>>(hArea, nullptr, shPart, Wt8, sb2,
                                                    nullptr, nullptr, nullptr);

    // ---- routed experts, batched single dispatches ----
    transpose_cvt<<<dim3(HFFN / 32, DMODEL / 32, NEXP), dim3(32, 8), 0, stream>>>(W1, Wt, DMODEL, HFFN);
    ffn_gemm<1, true><<<NEXP * 64 * 32, 256, 0, stream>>>(Xb, hArea, nullptr, Wt, b1,
                                                          nullptr, lists, counts);
    transpose_cvt<<<dim3(DMODEL / 32, HFFN / 32, NEXP), dim3(32, 8), 0, stream>>>(W2, Wt, HFFN, DMODEL);
    ffn_gemm<2, true><<<NEXP * 64 * 16, 256, 0, stream>>>(hArea, nullptr, (ushort*)out, Wt, b2,
                                                          gdense, lists, counts);

    combine_kernel<<<T_TOK * DMODEL / 1024, 256, 0, stream>>>(out, shPart);
}

// Round 11
// 1095.288 us; speedup vs baseline: 1.1189x; 1.0751x over previous
//
#include <hip/hip_runtime.h>
#include <hip/hip_bf16.h>

typedef __attribute__((ext_vector_type(8))) short short8;
typedef __attribute__((ext_vector_type(4))) float f32x4;

#define T_TOK 8192
#define DMODEL 1024
#define HFFN 4096
#define NEXP 4

__device__ __forceinline__ ushort f2b(float f) {
    __hip_bfloat16 h = __float2bfloat16(f);
    return __builtin_bit_cast(ushort, h);
}
__device__ __forceinline__ float b2f(unsigned u) {  // low 16 bits = bf16
    return __builtin_bit_cast(float, u << 16);
}

__device__ __forceinline__ void glds16(const void* g, void* l) {
    __builtin_amdgcn_global_load_lds(
        (__attribute__((address_space(1))) void*)g,
        (__attribute__((address_space(3))) void*)l, 16, 0, 0);
}

// ---------------- gate + x->bf16 fusion + ballot routing + inverse index -----
// lists[e*T+p] = tok ;  inv[2t+s] = (e<<16) | p  (s = top-1 / top-2 pick)
__global__ __launch_bounds__(256) void gate_kernel(
        const float* __restrict__ x, const float* __restrict__ gw,
        ushort* __restrict__ Xb, float* __restrict__ gdense,
        int* __restrict__ counts, int* __restrict__ lists,
        int* __restrict__ inv) {
    const int lane = threadIdx.x & 63;
    const int w = threadIdx.x >> 6;
    __shared__ int top2s[32];

    float4 wv[4][4];
#pragma unroll
    for (int p = 0; p < 4; p++)
#pragma unroll
        for (int e = 0; e < 4; e++)
            wv[p][e] = *(const float4*)&gw[e * DMODEL + p * 256 + lane * 4];

    const int t0 = blockIdx.x * 32 + w * 8;
#pragma unroll
    for (int i = 0; i < 8; i++) {
        const int t = t0 + i;
        const float* xr = x + (size_t)t * DMODEL;
        ushort* xbr = Xb + (size_t)t * DMODEL;
        float acc[4] = {0.f, 0.f, 0.f, 0.f};
#pragma unroll
        for (int p = 0; p < 4; p++) {
            float4 xv = *(const float4*)&xr[p * 256 + lane * 4];
            ushort4 o;
            o.x = f2b(xv.x); o.y = f2b(xv.y); o.z = f2b(xv.z); o.w = f2b(xv.w);
            *(ushort4*)&xbr[p * 256 + lane * 4] = o;
#pragma unroll
            for (int e = 0; e < 4; e++)
                acc[e] += xv.x * wv[p][e].x + xv.y * wv[p][e].y +
                          xv.z * wv[p][e].z + xv.w * wv[p][e].w;
        }
#pragma unroll
        for (int e = 0; e < 4; e++)
#pragma unroll
            for (int s = 1; s < 64; s <<= 1) acc[e] += __shfl_xor(acc[e], s);
        if (lane == 0) {
            int i0 = 0; float v0 = acc[0];
#pragma unroll
            for (int e = 1; e < 4; e++) if (acc[e] > v0) { v0 = acc[e]; i0 = e; }
            int i1 = -1; float v1 = -INFINITY;
#pragma unroll
            for (int e = 0; e < 4; e++) if (e != i0 && acc[e] > v1) { v1 = acc[e]; i1 = e; }
            float e1 = expf(v1 - v0);
            float w0 = 1.0f / (1.0f + e1);
            float w1 = e1 / (1.0f + e1);
            float o[4] = {0.f, 0.f, 0.f, 0.f};
            o[i0] = w0; o[i1] = w1;
            *(float4*)&gdense[t * 4] = make_float4(o[0], o[1], o[2], o[3]);
            top2s[w * 8 + i] = i0 | (i1 << 4);
        }
    }
    __syncthreads();
    if (w == 0) {
        int i0 = -1, i1 = -1;
        if (lane < 32) {
            const int pk = top2s[lane];
            i0 = pk & 15; i1 = pk >> 4;
        }
        const unsigned long long below = (1ull << lane) - 1;
        const int t = blockIdx.x * 32 + lane;
#pragma unroll
        for (int e = 0; e < 4; e++) {
            unsigned long long m0 = __ballot(i0 == e);
            unsigned long long m1 = __ballot(i1 == e);
            const int c0 = __popcll(m0);
            const int c1 = __popcll(m1);
            int base = 0;
            if (lane == 0 && (c0 + c1) > 0) base = atomicAdd(&counts[e], c0 + c1);
            base = __shfl(base, 0);
            if (i0 == e) {
                const int p = base + __popcll(m0 & below);
                lists[e * T_TOK + p] = t;
                inv[2 * t] = (e << 16) | p;
            }
            if (i1 == e) {
                const int p = base + c0 + __popcll(m1 & below);
                lists[e * T_TOK + p] = t;
                inv[2 * t + 1] = (e << 16) | p;
            }
        }
    }
}

// ---------------- fp32 [Kd][Nd] -> bf16 [Nd][Kd] (batched over z) -------------
__global__ void transpose_cvt(const float* __restrict__ in, ushort* __restrict__ out,
                              int Kd, int Nd) {
    __shared__ float tile[32][33];
    const size_t mat = (size_t)Kd * Nd;
    const float* ip = in + (size_t)blockIdx.z * mat;
    ushort* op = out + (size_t)blockIdx.z * mat;
    const int n0 = blockIdx.x * 32, k0 = blockIdx.y * 32;
    const int tx = threadIdx.x, ty = threadIdx.y;  // (32, 8)
#pragma unroll
    for (int j = 0; j < 4; j++)
        tile[ty + j * 8][tx] = ip[(size_t)(k0 + ty + j * 8) * Nd + n0 + tx];
    __syncthreads();
#pragma unroll
    for (int j = 0; j < 4; j++)
        op[(size_t)(n0 + ty + j * 8) * Kd + k0 + tx] = f2b(tile[tx][ty + j * 8]);
}

// -------- FFN GEMM (2-phase dbuf, m97 core), 128x128 tile, batched sections ---
// PHASE1: A rows from Xb (gathered if ROUTED); h[(pfx+r)][c] = gelu(v+b1)
// PHASE2 ROUTED:  parts[(pfx+r)*D + c] = bf16(g*(v+b2))   (contiguous, write-only)
// PHASE2 !ROUTED: yOut[r*D + c] = v + sb2                 (fp32 store to out)
template <int PHASE, bool ROUTED>
__launch_bounds__(256)
__global__ void ffn_gemm(const ushort* __restrict__ Abase,
                         ushort* __restrict__ hOut,
                         ushort* __restrict__ uOut,
                         float* __restrict__ yOut,
                         const ushort* __restrict__ Wbase,
                         const float* __restrict__ biasBase,
                         const float* __restrict__ gdense,
                         const int* __restrict__ lists,
                         const int* __restrict__ counts) {
    constexpr int Nn = (PHASE == 1) ? HFFN : DMODEL;
    constexpr int Kd = (PHASE == 1) ? DMODEL : HFFN;
    constexpr int NC = Nn / 128;
    constexpr int SEC = 64 * NC;          // capacity row-tiles(64) x col-tiles
    constexpr int BK = 32;

    __shared__ ushort As[2][128 * BK];
    __shared__ ushort Bs[2][128 * BK];

    int sec, id;
    if (ROUTED) { sec = blockIdx.x / SEC; id = blockIdx.x % SEC; }
    else        { sec = 0; id = blockIdx.x; }
    // bijective XCD chunking (SEC % 8 == 0): each XCD owns contiguous row-tiles
    id = (id & 7) * (SEC >> 3) + (id >> 3);

    const int cnt = ROUTED ? counts[sec] : T_TOK;
    const int row0 = (id / NC) * 128;
    if (row0 >= cnt) return;
    const int col0 = (id % NC) * 128;
    int pfx = 0;
    if (ROUTED) for (int i = 0; i < sec; i++) pfx += counts[i];
    const int* list_s = ROUTED ? (lists + sec * T_TOK) : nullptr;
    const ushort* Bt = Wbase + (ROUTED ? (size_t)sec * Kd * Nn : 0);
    const float* bias = biasBase + (ROUTED ? sec * Nn : 0);

    const int tid = threadIdx.x;
    const int lane = tid & 63, wid = tid >> 6;
    const int rowbase = (wid >> 1) * 64;
    const int colbase = (wid & 1) * 64;

    const int s_r = tid >> 2;
    const int s_k = (tid & 3) * 8;

    int l0 = row0 + s_r;       if (l0 >= cnt) l0 = cnt - 1;
    int l1 = row0 + 64 + s_r;  if (l1 >= cnt) l1 = cnt - 1;
    size_t ar0, ar1;
    if (PHASE == 1) {
        ar0 = ROUTED ? (size_t)lists[sec * T_TOK + l0] : (size_t)l0;
        ar1 = ROUTED ? (size_t)lists[sec * T_TOK + l1] : (size_t)l1;
    } else {
        ar0 = (size_t)(pfx + l0);
        ar1 = (size_t)(pfx + l1);
    }
    const ushort* Ap0 = Abase + ar0 * Kd + s_k;
    const ushort* Ap1 = Abase + ar1 * Kd + s_k;
    const ushort* Bp0 = Bt + (size_t)(col0 + s_r) * Kd + s_k;
    const ushort* Bp1 = Bt + (size_t)(col0 + 64 + s_r) * Kd + s_k;

    auto stage = [&](int buf, int k0) {
        glds16(Ap0 + k0, &As[buf][wid * 512]);
        glds16(Ap1 + k0, &As[buf][2048 + wid * 512]);
        glds16(Bp0 + k0, &Bs[buf][wid * 512]);
        glds16(Bp1 + k0, &Bs[buf][2048 + wid * 512]);
    };

    f32x4 acc[4][4] = {};
    const int lr = lane & 15, lk = (lane >> 4) * 8;

    auto compute = [&](int buf) {
        short8 af[4], bf[4];
#pragma unroll
        for (int m = 0; m < 4; m++)
            af[m] = *(const short8*)&As[buf][(rowbase + m * 16 + lr) * BK + lk];
#pragma unroll
        for (int n = 0; n < 4; n++)
            bf[n] = *(const short8*)&Bs[buf][(colbase + n * 16 + lr) * BK + lk];
#pragma unroll
        for (int m = 0; m < 4; m++)
#pragma unroll
            for (int n = 0; n < 4; n++)
                acc[m][n] = __builtin_amdgcn_mfma_f32_16x16x32_bf16(af[m], bf[n], acc[m][n], 0, 0, 0);
    };

    stage(0, 0);
    __syncthreads();
    int cur = 0;
    constexpr int nk = Kd / BK;
    for (int t = 0; t < nk - 1; ++t) {
        stage(cur ^ 1, (t + 1) * BK);
        compute(cur);
        __syncthreads();
        cur ^= 1;
    }
    compute(cur);

    // epilogue: C/D layout col = lane&15, row = (lane>>4)*4 + j  [verified]
    const int lq = lane >> 4;
#pragma unroll
    for (int m = 0; m < 4; m++) {
        const int r_base = row0 + rowbase + m * 16 + lq * 4;
#pragma unroll
        for (int n = 0; n < 4; n++) {
            const int c = col0 + colbase + n * 16 + lr;
            const float b = bias[c];
#pragma unroll
            for (int j = 0; j < 4; j++) {
                const int r = r_base + j;
                if (r >= cnt) continue;
                float v = acc[m][n][j] + b;
                if (PHASE == 1) {
                    // gelu(v) = v*sigmoid(1.5957691*t2); exp2 const = 1.5957691*log2e
                    float v2 = v * v;
                    float t2 = __builtin_fmaf(0.044715f, v2 * v, v);
                    float e = __builtin_amdgcn_exp2f(2.3022082f * t2);
                    float rr = __builtin_amdgcn_rcpf(e + 1.0f);
                    hOut[(size_t)(pfx + r) * HFFN + c] = f2b(v - v * rr);
                } else if (ROUTED) {
                    const int tok = list_s[r];
                    const float g = gdense[tok * 4 + sec];
                    uOut[(size_t)(pfx + r) * DMODEL + c] = f2b(g * v);
                } else {
                    yOut[(size_t)r * DMODEL + c] = v;
                }
            }
        }
    }
}

// -------- combine: out[t][c] (holds shared fp32) += parts[idx0] + parts[idx1] --
__global__ __launch_bounds__(256) void combine_kernel(
        float* __restrict__ out, const ushort* __restrict__ parts,
        const int* __restrict__ inv, const int* __restrict__ counts) {
    const int t = blockIdx.x;
    const int c = threadIdx.x * 4;
    const int c0 = counts[0], c1 = counts[1], c2 = counts[2];
    const int v0 = inv[2 * t], v1 = inv[2 * t + 1];
    const int e0 = v0 >> 16, e1 = v1 >> 16;
    const int pfx0 = (e0 > 0 ? c0 : 0) + (e0 > 1 ? c1 : 0) + (e0 > 2 ? c2 : 0);
    const int pfx1 = (e1 > 0 ? c0 : 0) + (e1 > 1 ? c1 : 0) + (e1 > 2 ? c2 : 0);
    const size_t r0 = (size_t)(pfx0 + (v0 & 0xffff)) * DMODEL + c;
    const size_t r1 = (size_t)(pfx1 + (v1 & 0xffff)) * DMODEL + c;
    float* op = out + (size_t)t * DMODEL + c;
    float4 o = *(float4*)op;
    ushort4 a = *(const ushort4*)&parts[r0];
    ushort4 b = *(const ushort4*)&parts[r1];
    o.x += b2f(a.x) + b2f(b.x);
    o.y += b2f(a.y) + b2f(b.y);
    o.z += b2f(a.z) + b2f(b.z);
    o.w += b2f(a.w) + b2f(b.w);
    *(float4*)op = o;
}

extern "C" void kernel_launch(void* const* d_in, const int* in_sizes, int n_in,
                              void* d_out, int out_size, void* d_ws, size_t ws_size,
                              hipStream_t stream) {
    const float* x      = (const float*)d_in[0];
    const float* gate_w = (const float*)d_in[1];
    const float* W1     = (const float*)d_in[2];
    const float* b1     = (const float*)d_in[3];
    const float* W2     = (const float*)d_in[4];
    const float* b2     = (const float*)d_in[5];
    const float* sW1    = (const float*)d_in[6];
    const float* sb1    = (const float*)d_in[7];
    const float* sW2    = (const float*)d_in[8];
    const float* sb2    = (const float*)d_in[9];
    float* out = (float*)d_out;

    // ---- lifetime-phased workspace, peak ~192.3 MiB (R10-proven safe) ----
    // [0,128)   hArea: shared h rows [0,8192), then routed h rows [0,16384)
    // [128,144) Xb (live gate..routedG1) ; later overlaid by W2t
    // [144,176) W1t (live ..routedG1); sW1t@[144,152) sW2t@[152,160) earlier
    // [128,160) W2t (written AFTER routedG1, live routedG2)
    // [160,192) parts (routed G2 out, 32 MiB; aliases dead W1t-hi)
    // [192,..)  gdense 128K | counts 256B | lists 128K | inv 64K
    char* ws = (char*)d_ws;
    ushort* hArea  = (ushort*)(ws);
    ushort* Xb     = (ushort*)(ws + (size_t)128 * 1024 * 1024);
    ushort* W1t    = (ushort*)(ws + (size_t)144 * 1024 * 1024);
    ushort* sW1t   = W1t;                                            // [144,152)
    ushort* sW2t   = (ushort*)(ws + (size_t)152 * 1024 * 1024);
    ushort* W2t    = (ushort*)(ws + (size_t)128 * 1024 * 1024);      // after routedG1
    ushort* parts  = (ushort*)(ws + (size_t)160 * 1024 * 1024);
    float*  gdense = (float*)(ws + (size_t)192 * 1024 * 1024);
    int*    counts = (int*)(ws + (size_t)192 * 1024 * 1024 + 131072);
    int*    lists  = (int*)(ws + (size_t)192 * 1024 * 1024 + 131072 + 256);
    int*    inv    = (int*)(ws + (size_t)192 * 1024 * 1024 + 131072 + 256 + 131072);

    hipMemsetAsync(counts, 0, NEXP * sizeof(int), stream);

    // gate + fused x->bf16
    gate_kernel<<<T_TOK / 32, 256, 0, stream>>>(x, gate_w, Xb, gdense, counts, lists, inv);

    // ---- shared expert (h rows [0,8192) of hArea; out gets fp32 shared y) ----
    transpose_cvt<<<dim3(HFFN / 32, DMODEL / 32, 1), dim3(32, 8), 0, stream>>>(sW1, sW1t, DMODEL, HFFN);
    transpose_cvt<<<dim3(DMODEL / 32, HFFN / 32, 1), dim3(32, 8), 0, stream>>>(sW2, sW2t, HFFN, DMODEL);
    ffn_gemm<1, false><<<64 * 32, 256, 0, stream>>>(Xb, hArea, nullptr, nullptr, sW1t, sb1,
                                                    nullptr, nullptr, nullptr);
    ffn_gemm<2, false><<<64 * 8, 256, 0, stream>>>(hArea, nullptr, nullptr, out, sW2t, sb2,
                                                   nullptr, nullptr, nullptr);

    // ---- routed experts, batched ----
    transpose_cvt<<<dim3(HFFN / 32, DMODEL / 32, NEXP), dim3(32, 8), 0, stream>>>(W1, W1t, DMODEL, HFFN);
    ffn_gemm<1, true><<<NEXP * 64 * 32, 256, 0, stream>>>(Xb, hArea, nullptr, nullptr, W1t, b1,
                                                          nullptr, lists, counts);
    transpose_cvt<<<dim3(DMODEL / 32, HFFN / 32, NEXP), dim3(32, 8), 0, stream>>>(W2, W2t, HFFN, DMODEL);
    ffn_gemm<2, true><<<NEXP * 64 * 8, 256, 0, stream>>>(hArea, nullptr, parts, nullptr, W2t, b2,
                                                         gdense, lists, counts);

    combine_kernel<<<T_TOK, 256, 0, stream>>>(out, parts, inv, counts);
}

// Round 12
// 757.437 us; speedup vs baseline: 1.6179x; 1.4460x over previous
//
#include <hip/hip_runtime.h>
#include <hip/hip_bf16.h>

typedef __attribute__((ext_vector_type(8))) short short8;
typedef __attribute__((ext_vector_type(4))) float f32x4;

#define T_TOK 8192
#define DMODEL 1024
#define HFFN 4096
#define NEXP 4

__device__ __forceinline__ ushort f2b(float f) {
    __hip_bfloat16 h = __float2bfloat16(f);
    return __builtin_bit_cast(ushort, h);
}
__device__ __forceinline__ float b2f(unsigned u) {  // low 16 bits = bf16
    return __builtin_bit_cast(float, u << 16);
}

__device__ __forceinline__ void glds16(const void* g, void* l) {
    __builtin_amdgcn_global_load_lds(
        (__attribute__((address_space(1))) void*)g,
        (__attribute__((address_space(3))) void*)l, 16, 0, 0);
}

// ---------------- gate + x->bf16 fusion + ballot routing + inverse index -----
// lists[e*T+p] = tok ;  inv[2t+s] = (e<<16) | p  (s = top-1 / top-2 pick)
__global__ __launch_bounds__(256) void gate_kernel(
        const float* __restrict__ x, const float* __restrict__ gw,
        ushort* __restrict__ Xb, float* __restrict__ gdense,
        int* __restrict__ counts, int* __restrict__ lists,
        int* __restrict__ inv) {
    const int lane = threadIdx.x & 63;
    const int w = threadIdx.x >> 6;
    __shared__ int top2s[32];

    float4 wv[4][4];
#pragma unroll
    for (int p = 0; p < 4; p++)
#pragma unroll
        for (int e = 0; e < 4; e++)
            wv[p][e] = *(const float4*)&gw[e * DMODEL + p * 256 + lane * 4];

    const int t0 = blockIdx.x * 32 + w * 8;
#pragma unroll
    for (int i = 0; i < 8; i++) {
        const int t = t0 + i;
        const float* xr = x + (size_t)t * DMODEL;
        ushort* xbr = Xb + (size_t)t * DMODEL;
        float acc[4] = {0.f, 0.f, 0.f, 0.f};
#pragma unroll
        for (int p = 0; p < 4; p++) {
            float4 xv = *(const float4*)&xr[p * 256 + lane * 4];
            ushort4 o;
            o.x = f2b(xv.x); o.y = f2b(xv.y); o.z = f2b(xv.z); o.w = f2b(xv.w);
            *(ushort4*)&xbr[p * 256 + lane * 4] = o;
#pragma unroll
            for (int e = 0; e < 4; e++)
                acc[e] += xv.x * wv[p][e].x + xv.y * wv[p][e].y +
                          xv.z * wv[p][e].z + xv.w * wv[p][e].w;
        }
#pragma unroll
        for (int e = 0; e < 4; e++)
#pragma unroll
            for (int s = 1; s < 64; s <<= 1) acc[e] += __shfl_xor(acc[e], s);
        if (lane == 0) {
            int i0 = 0; float v0 = acc[0];
#pragma unroll
            for (int e = 1; e < 4; e++) if (acc[e] > v0) { v0 = acc[e]; i0 = e; }
            int i1 = -1; float v1 = -INFINITY;
#pragma unroll
            for (int e = 0; e < 4; e++) if (e != i0 && acc[e] > v1) { v1 = acc[e]; i1 = e; }
            float e1 = expf(v1 - v0);
            float w0 = 1.0f / (1.0f + e1);
            float w1 = e1 / (1.0f + e1);
            float o[4] = {0.f, 0.f, 0.f, 0.f};
            o[i0] = w0; o[i1] = w1;
            *(float4*)&gdense[t * 4] = make_float4(o[0], o[1], o[2], o[3]);
            top2s[w * 8 + i] = i0 | (i1 << 4);
        }
    }
    __syncthreads();
    if (w == 0) {
        int i0 = -1, i1 = -1;
        if (lane < 32) {
            const int pk = top2s[lane];
            i0 = pk & 15; i1 = pk >> 4;
        }
        const unsigned long long below = (1ull << lane) - 1;
        const int t = blockIdx.x * 32 + lane;
#pragma unroll
        for (int e = 0; e < 4; e++) {
            unsigned long long m0 = __ballot(i0 == e);
            unsigned long long m1 = __ballot(i1 == e);
            const int c0 = __popcll(m0);
            const int c1 = __popcll(m1);
            int base = 0;
            if (lane == 0 && (c0 + c1) > 0) base = atomicAdd(&counts[e], c0 + c1);
            base = __shfl(base, 0);
            if (i0 == e) {
                const int p = base + __popcll(m0 & below);
                lists[e * T_TOK + p] = t;
                inv[2 * t] = (e << 16) | p;
            }
            if (i1 == e) {
                const int p = base + c0 + __popcll(m1 & below);
                lists[e * T_TOK + p] = t;
                inv[2 * t + 1] = (e << 16) | p;
            }
        }
    }
}

// ---------------- fp32 [Kd][Nd] -> bf16 [Nd][Kd] (batched over z) -------------
__global__ void transpose_cvt(const float* __restrict__ in, ushort* __restrict__ out,
                              int Kd, int Nd) {
    __shared__ float tile[32][33];
    const size_t mat = (size_t)Kd * Nd;
    const float* ip = in + (size_t)blockIdx.z * mat;
    ushort* op = out + (size_t)blockIdx.z * mat;
    const int n0 = blockIdx.x * 32, k0 = blockIdx.y * 32;
    const int tx = threadIdx.x, ty = threadIdx.y;  // (32, 8)
#pragma unroll
    for (int j = 0; j < 4; j++)
        tile[ty + j * 8][tx] = ip[(size_t)(k0 + ty + j * 8) * Nd + n0 + tx];
    __syncthreads();
#pragma unroll
    for (int j = 0; j < 4; j++)
        op[(size_t)(n0 + ty + j * 8) * Kd + k0 + tx] = f2b(tile[tx][ty + j * 8]);
}

// -------- FFN GEMM (2-phase dbuf, m97 core), 128x128 tile, batched sections ---
// Grid id layout: rt OUTER, (sec,ct) inner, XCD-bijective inner remap:
//   rt = id / P; pos = id % P; inner = (pos&7)*(P/8) + (pos>>3);
//   sec = inner / NC; ct = inner % NC.
// -> early-exit rows (rt >= cnt/128) idle UNIFORMLY across XCDs, and each XCD
//    owns a fixed (sec, col-range) whose B-panels stay L2-resident over rt.
// PHASE1: A rows from Xb (gathered if ROUTED); h[(pfx+r)][c] = gelu(v+b1)
// PHASE2 ROUTED:  parts[(pfx+r)*D + c] = bf16(g*(v+b2))   (contiguous, write-only)
// PHASE2 !ROUTED: yOut[r*D + c] = v + sb2                 (fp32 store to out)
template <int PHASE, bool ROUTED>
__launch_bounds__(256)
__global__ void ffn_gemm(const ushort* __restrict__ Abase,
                         ushort* __restrict__ hOut,
                         ushort* __restrict__ uOut,
                         float* __restrict__ yOut,
                         const ushort* __restrict__ Wbase,
                         const float* __restrict__ biasBase,
                         const float* __restrict__ gdense,
                         const int* __restrict__ lists,
                         const int* __restrict__ counts) {
    constexpr int Nn = (PHASE == 1) ? HFFN : DMODEL;
    constexpr int Kd = (PHASE == 1) ? DMODEL : HFFN;
    constexpr int NC = Nn / 128;
    constexpr int NSEC = ROUTED ? NEXP : 1;
    constexpr int P = NSEC * NC;          // inner id space; P % 8 == 0 (128/32/32/8)
    constexpr int PER8 = (P >= 8) ? P / 8 : 1;
    constexpr int BK = 32;

    __shared__ ushort As[2][128 * BK];
    __shared__ ushort Bs[2][128 * BK];

    const int id = blockIdx.x;
    const int rt = id / P;
    const int pos = id % P;
    const int inner = (pos & 7) * PER8 + (pos >> 3);
    const int sec = inner / NC;
    const int ct = inner % NC;

    const int cnt = ROUTED ? counts[sec] : T_TOK;
    const int row0 = rt * 128;
    if (row0 >= cnt) return;
    const int col0 = ct * 128;
    int pfx = 0;
    if (ROUTED) for (int i = 0; i < sec; i++) pfx += counts[i];
    const int* list_s = ROUTED ? (lists + sec * T_TOK) : nullptr;
    const ushort* Bt = Wbase + (ROUTED ? (size_t)sec * Kd * Nn : 0);
    const float* bias = biasBase + (ROUTED ? sec * Nn : 0);

    const int tid = threadIdx.x;
    const int lane = tid & 63, wid = tid >> 6;
    const int rowbase = (wid >> 1) * 64;
    const int colbase = (wid & 1) * 64;

    const int s_r = tid >> 2;
    const int s_k = (tid & 3) * 8;

    int l0 = row0 + s_r;       if (l0 >= cnt) l0 = cnt - 1;
    int l1 = row0 + 64 + s_r;  if (l1 >= cnt) l1 = cnt - 1;
    size_t ar0, ar1;
    if (PHASE == 1) {
        ar0 = ROUTED ? (size_t)list_s[l0] : (size_t)l0;
        ar1 = ROUTED ? (size_t)list_s[l1] : (size_t)l1;
    } else {
        ar0 = (size_t)(pfx + l0);
        ar1 = (size_t)(pfx + l1);
    }
    const ushort* Ap0 = Abase + ar0 * Kd + s_k;
    const ushort* Ap1 = Abase + ar1 * Kd + s_k;
    const ushort* Bp0 = Bt + (size_t)(col0 + s_r) * Kd + s_k;
    const ushort* Bp1 = Bt + (size_t)(col0 + 64 + s_r) * Kd + s_k;

    auto stage = [&](int buf, int k0) {
        glds16(Ap0 + k0, &As[buf][wid * 512]);
        glds16(Ap1 + k0, &As[buf][2048 + wid * 512]);
        glds16(Bp0 + k0, &Bs[buf][wid * 512]);
        glds16(Bp1 + k0, &Bs[buf][2048 + wid * 512]);
    };

    f32x4 acc[4][4] = {};
    const int lr = lane & 15, lk = (lane >> 4) * 8;

    auto compute = [&](int buf) {
        short8 af[4], bf[4];
#pragma unroll
        for (int m = 0; m < 4; m++)
            af[m] = *(const short8*)&As[buf][(rowbase + m * 16 + lr) * BK + lk];
#pragma unroll
        for (int n = 0; n < 4; n++)
            bf[n] = *(const short8*)&Bs[buf][(colbase + n * 16 + lr) * BK + lk];
#pragma unroll
        for (int m = 0; m < 4; m++)
#pragma unroll
            for (int n = 0; n < 4; n++)
                acc[m][n] = __builtin_amdgcn_mfma_f32_16x16x32_bf16(af[m], bf[n], acc[m][n], 0, 0, 0);
    };

    stage(0, 0);
    __syncthreads();
    int cur = 0;
    constexpr int nk = Kd / BK;
    for (int t = 0; t < nk - 1; ++t) {
        stage(cur ^ 1, (t + 1) * BK);
        compute(cur);
        __syncthreads();
        cur ^= 1;
    }
    compute(cur);

    // epilogue: C/D layout col = lane&15, row = (lane>>4)*4 + j  [verified]
    const int lq = lane >> 4;
#pragma unroll
    for (int m = 0; m < 4; m++) {
        const int r_base = row0 + rowbase + m * 16 + lq * 4;
#pragma unroll
        for (int n = 0; n < 4; n++) {
            const int c = col0 + colbase + n * 16 + lr;
            const float b = bias[c];
#pragma unroll
            for (int j = 0; j < 4; j++) {
                const int r = r_base + j;
                if (r >= cnt) continue;
                float v = acc[m][n][j] + b;
                if (PHASE == 1) {
                    // gelu(v) = v*sigmoid(1.5957691*t2); exp2 const = 1.5957691*log2e
                    float v2 = v * v;
                    float t2 = __builtin_fmaf(0.044715f, v2 * v, v);
                    float e = __builtin_amdgcn_exp2f(2.3022082f * t2);
                    float rr = __builtin_amdgcn_rcpf(e + 1.0f);
                    hOut[(size_t)(pfx + r) * HFFN + c] = f2b(v - v * rr);
                } else if (ROUTED) {
                    const int tok = list_s[r];
                    const float g = gdense[tok * 4 + sec];
                    uOut[(size_t)(pfx + r) * DMODEL + c] = f2b(g * v);
                } else {
                    yOut[(size_t)r * DMODEL + c] = v;
                }
            }
        }
    }
}

// -------- combine: out[t][c] (holds shared fp32) += parts[idx0] + parts[idx1] --
__global__ __launch_bounds__(256) void combine_kernel(
        float* __restrict__ out, const ushort* __restrict__ parts,
        const int* __restrict__ inv, const int* __restrict__ counts) {
    const int t = blockIdx.x;
    const int c = threadIdx.x * 4;
    const int c0 = counts[0], c1 = counts[1], c2 = counts[2];
    const int v0 = inv[2 * t], v1 = inv[2 * t + 1];
    const int e0 = v0 >> 16, e1 = v1 >> 16;
    const int pfx0 = (e0 > 0 ? c0 : 0) + (e0 > 1 ? c1 : 0) + (e0 > 2 ? c2 : 0);
    const int pfx1 = (e1 > 0 ? c0 : 0) + (e1 > 1 ? c1 : 0) + (e1 > 2 ? c2 : 0);
    const size_t r0 = (size_t)(pfx0 + (v0 & 0xffff)) * DMODEL + c;
    const size_t r1 = (size_t)(pfx1 + (v1 & 0xffff)) * DMODEL + c;
    float* op = out + (size_t)t * DMODEL + c;
    float4 o = *(float4*)op;
    ushort4 a = *(const ushort4*)&parts[r0];
    ushort4 b = *(const ushort4*)&parts[r1];
    o.x += b2f(a.x) + b2f(b.x);
    o.y += b2f(a.y) + b2f(b.y);
    o.z += b2f(a.z) + b2f(b.z);
    o.w += b2f(a.w) + b2f(b.w);
    *(float4*)op = o;
}

extern "C" void kernel_launch(void* const* d_in, const int* in_sizes, int n_in,
                              void* d_out, int out_size, void* d_ws, size_t ws_size,
                              hipStream_t stream) {
    const float* x      = (const float*)d_in[0];
    const float* gate_w = (const float*)d_in[1];
    const float* W1     = (const float*)d_in[2];
    const float* b1     = (const float*)d_in[3];
    const float* W2     = (const float*)d_in[4];
    const float* b2     = (const float*)d_in[5];
    const float* sW1    = (const float*)d_in[6];
    const float* sb1    = (const float*)d_in[7];
    const float* sW2    = (const float*)d_in[8];
    const float* sb2    = (const float*)d_in[9];
    float* out = (float*)d_out;

    // ---- lifetime-phased workspace, peak ~192.3 MiB (R10/R11-proven safe) ----
    char* ws = (char*)d_ws;
    ushort* hArea  = (ushort*)(ws);
    ushort* Xb     = (ushort*)(ws + (size_t)128 * 1024 * 1024);
    ushort* W1t    = (ushort*)(ws + (size_t)144 * 1024 * 1024);
    ushort* sW1t   = W1t;                                            // [144,152)
    ushort* sW2t   = (ushort*)(ws + (size_t)152 * 1024 * 1024);
    ushort* W2t    = (ushort*)(ws + (size_t)128 * 1024 * 1024);      // after routedG1
    ushort* parts  = (ushort*)(ws + (size_t)160 * 1024 * 1024);
    float*  gdense = (float*)(ws + (size_t)192 * 1024 * 1024);
    int*    counts = (int*)(ws + (size_t)192 * 1024 * 1024 + 131072);
    int*    lists  = (int*)(ws + (size_t)192 * 1024 * 1024 + 131072 + 256);
    int*    inv    = (int*)(ws + (size_t)192 * 1024 * 1024 + 131072 + 256 + 131072);

    hipMemsetAsync(counts, 0, NEXP * sizeof(int), stream);

    // gate + fused x->bf16
    gate_kernel<<<T_TOK / 32, 256, 0, stream>>>(x, gate_w, Xb, gdense, counts, lists, inv);

    // ---- shared expert (h rows [0,8192) of hArea; out gets fp32 shared y) ----
    transpose_cvt<<<dim3(HFFN / 32, DMODEL / 32, 1), dim3(32, 8), 0, stream>>>(sW1, sW1t, DMODEL, HFFN);
    transpose_cvt<<<dim3(DMODEL / 32, HFFN / 32, 1), dim3(32, 8), 0, stream>>>(sW2, sW2t, HFFN, DMODEL);
    ffn_gemm<1, false><<<64 * 32, 256, 0, stream>>>(Xb, hArea, nullptr, nullptr, sW1t, sb1,
                                                    nullptr, nullptr, nullptr);
    ffn_gemm<2, false><<<64 * 8, 256, 0, stream>>>(hArea, nullptr, nullptr, out, sW2t, sb2,
                                                   nullptr, nullptr, nullptr);

    // ---- routed experts, batched ----
    transpose_cvt<<<dim3(HFFN / 32, DMODEL / 32, NEXP), dim3(32, 8), 0, stream>>>(W1, W1t, DMODEL, HFFN);
    ffn_gemm<1, true><<<64 * NEXP * 32, 256, 0, stream>>>(Xb, hArea, nullptr, nullptr, W1t, b1,
                                                          nullptr, lists, counts);
    transpose_cvt<<<dim3(DMODEL / 32, HFFN / 32, NEXP), dim3(32, 8), 0, stream>>>(W2, W2t, HFFN, DMODEL);
    ffn_gemm<2, true><<<64 * NEXP * 8, 256, 0, stream>>>(hArea, nullptr, parts, nullptr, W2t, b2,
                                                         gdense, lists, counts);

    combine_kernel<<<T_TOK, 256, 0, stream>>>(out, parts, inv, counts);
}